// Round 4
// baseline (95.366 us; speedup 1.0000x reference)
//
#include <hip/hip_runtime.h>
#include <math.h>

#define N 8192
#define D 3072
#define NCHUNK 16777215u  // (N*N - 4) / 4 aligned float4 chunks in K
#define TTOT   2097152u   // 8192 worker blocks * 256 threads

typedef float f4 __attribute__((ext_vector_type(4)));

// Kernel 1: one WAVE per row (4 rows per 256-thread block, no LDS, no barrier).
// One pass over x: row sum S and dot(x[i,:], w). Epilogue: e[i]=exp(S),
// r[i]=exp(-S). e stored at ws+1 so e+j is 16B-aligned for j ≡ 3 (mod 4).
__global__ __launch_bounds__(256) void rowsum_dot_kernel(
    const float* __restrict__ x, const float* __restrict__ w,
    float* __restrict__ ws_e, float* __restrict__ r,
    float* __restrict__ pred) {
    const int wave = threadIdx.x >> 6;
    const int lane = threadIdx.x & 63;
    const int i = blockIdx.x * 4 + wave;
    const float* xrow = x + (size_t)i * D;

    float sum = 0.f, dot = 0.f;
    #pragma unroll
    for (int k = 0; k < 12; ++k) {
        const int idx = (k * 64 + lane) * 4;
        const f4 xv = *reinterpret_cast<const f4*>(xrow + idx);
        const f4 wv = *reinterpret_cast<const f4*>(w + idx);
        sum += (xv.x + xv.y) + (xv.z + xv.w);
        dot += xv.x * wv.x + xv.y * wv.y + xv.z * wv.z + xv.w * wv.w;
    }
    #pragma unroll
    for (int off = 32; off > 0; off >>= 1) {
        sum += __shfl_down(sum, off, 64);
        dot += __shfl_down(dot, off, 64);
    }
    if (lane == 0) {
        ws_e[1 + i] = __expf(sum);   // e[i]
        r[i]        = __expf(-sum);  // exp(-s[i])
        pred[i]     = dot + w[D];    // + bias
    }
}

// Kernel 2: fused K-matrix + loss.
// Block 0: loss = 0.5*sqrt(sum((y-pred)^2))/N + sum(|w|), plus K's unaligned
//          3-float head and 1-float tail. Runs first, hides under the stream.
// Blocks 1..8192: flat-stream K as 16,777,215 aligned float4 chunks.
//   chunk c -> K-float g=3+4c, i=g>>13, j=g&8191; K[i,j]=e[j]*r[i].
//   Lanes take consecutive chunks -> 1KB/wave coalesced stores, uniform work.
__global__ __launch_bounds__(256) void kmat_loss_kernel(
    const float* __restrict__ ws_e, const float* __restrict__ r,
    float* __restrict__ Kf /* = d_out + 8193 */,
    const float* __restrict__ pred, const int* __restrict__ y,
    const float* __restrict__ w, float* __restrict__ loss_out) {
    const int tid = threadIdx.x;
    const float* __restrict__ e = ws_e + 1;

    if (blockIdx.x == 0) {
        float acc = 0.f;
        for (int i = tid; i < N; i += 256) {
            const float d = (float)y[i] - pred[i];
            acc += d * d;
        }
        float wacc = 0.f;
        for (int i = tid; i < D + 1; i += 256) wacc += fabsf(w[i]);
        #pragma unroll
        for (int off = 32; off > 0; off >>= 1) {
            acc  += __shfl_down(acc, off, 64);
            wacc += __shfl_down(wacc, off, 64);
        }
        __shared__ float la[4], lw[4];
        const int wv = tid >> 6;
        if ((tid & 63) == 0) { la[wv] = acc; lw[wv] = wacc; }
        __syncthreads();
        if (tid == 0) {
            const float a = (la[0] + la[1]) + (la[2] + la[3]);
            const float b = (lw[0] + lw[1]) + (lw[2] + lw[3]);
            loss_out[0] = 0.5f * sqrtf(a) / (float)N + b;
        }
        // K head (i=0, j=0..2) and tail (i=8191, j=8191)
        if (tid < 3) Kf[tid] = e[tid] * r[0];
        if (tid == 3) Kf[(size_t)N * N - 1] = e[N - 1] * r[N - 1];
        return;
    }

    const unsigned t = (blockIdx.x - 1) * 256 + tid;
    #pragma unroll
    for (int k = 0; k < 8; ++k) {
        const unsigned c = (unsigned)k * TTOT + t;
        if (c >= NCHUNK) break;  // only the very last chunk is skipped
        const unsigned g = 3 + 4 * c;
        const unsigned i = g >> 13;
        const unsigned j = g & 8191u;
        f4 o;
        if (j != 8191u) {
            const f4 ev = *reinterpret_cast<const f4*>(e + j);
            const float ri = r[i];
            o = ev * ri;
        } else {  // chunk spans rows i and i+1
            o.x = e[8191] * r[i];
            const float rn = r[i + 1];
            o.y = e[0] * rn; o.z = e[1] * rn; o.w = e[2] * rn;
        }
        *reinterpret_cast<f4*>(Kf + g) = o;  // Kf+g ≡ 0 (mod 4 floats)
    }
}

extern "C" void kernel_launch(void* const* d_in, const int* in_sizes, int n_in,
                              void* d_out, int out_size, void* d_ws, size_t ws_size,
                              hipStream_t stream) {
    const float* x = (const float*)d_in[0];   // [8192, 3072] f32
    const int*   y = (const int*)d_in[1];     // [8192, 1] i32
    const float* w = (const float*)d_in[2];   // [3073, 1] f32

    float* out  = (float*)d_out;
    float* pred = out;              // [8192]
    float* loss = out + N;          // [1]
    float* Kf   = out + N + 1;      // [8192, 8192], base ≡ 1 (mod 4 floats)

    float* ws_e = (float*)d_ws;     // e[i] at ws_e[1+i]
    float* r    = ws_e + 8200;      // [8192]

    rowsum_dot_kernel<<<N / 4, 256, 0, stream>>>(x, w, ws_e, r, pred);
    kmat_loss_kernel<<<8193, 256, 0, stream>>>(ws_e, r, Kf, pred, y, w, loss);
}